// Round 1
// baseline (614.422 us; speedup 1.0000x reference)
//
#include <hip/hip_runtime.h>
#include <math.h>

// NoisyTopkRouter: x[16384,2048] -> two skinny GEMMs vs W1/W2[2048,64],
// mixed = (xW1+b1) + noise*softplus(xW2+b2); outputs:
//   out0 sparse softmax [16384,64], out1 topk idx as float [16384,8], out2 full softmax [16384,64]
// Design: lane = expert (wave64 == 64 experts). Wave owns T=8 tokens.
// W chunks staged via LDS -> per-lane regs; x read as wave-uniform float4 (s_load),
// broadcast into v_fmac. fp32 FMA partials + fp64 chunk accumulation for topk-grade accuracy.

constexpr int ND    = 2048;   // n_embed
constexpr int NE    = 64;     // experts
constexpr int NK    = 8;      // top_k
constexpr int TPW   = 8;      // tokens per wave
constexpr int KC    = 32;     // K chunk
constexpr int NTOK  = 16384;  // B*S

__global__ __launch_bounds__(256, 2)
void router_kernel(const float* __restrict__ x,
                   const float* __restrict__ noise,
                   const float* __restrict__ W1,
                   const float* __restrict__ b1,
                   const float* __restrict__ W2,
                   const float* __restrict__ b2,
                   float* __restrict__ out_sparse,
                   float* __restrict__ out_idx,
                   float* __restrict__ out_full)
{
    __shared__ float w1s[KC * NE];
    __shared__ float w2s[KC * NE];

    const int lane = threadIdx.x & 63;
    const int wv   = __builtin_amdgcn_readfirstlane((int)(threadIdx.x >> 6));
    const long tok0 = ((long)blockIdx.x * 4 + wv) * TPW;

    double acc1[TPW], acc2[TPW];
    #pragma unroll
    for (int t = 0; t < TPW; ++t) { acc1[t] = 0.0; acc2[t] = 0.0; }

    for (int kc = 0; kc < ND; kc += KC) {
        __syncthreads();   // protect previous chunk's LDS reads
        for (int i = threadIdx.x; i < KC * NE; i += 256) {
            w1s[i] = W1[kc * NE + i];
            w2s[i] = W2[kc * NE + i];
        }
        __syncthreads();

        // per-lane register copy of this W chunk (lane = expert column)
        float w1r[KC], w2r[KC];
        #pragma unroll
        for (int j = 0; j < KC; ++j) {
            w1r[j] = w1s[j * NE + lane];   // consecutive lanes -> consecutive dwords: 2-way, free
            w2r[j] = w2s[j * NE + lane];
        }

        #pragma unroll
        for (int t = 0; t < TPW; ++t) {
            const float4* xp = (const float4*)(x + (size_t)(tok0 + t) * ND + kc);
            float p0 = 0.f, p1 = 0.f, p2 = 0.f, p3 = 0.f;
            float q0 = 0.f, q1 = 0.f, q2 = 0.f, q3 = 0.f;
            #pragma unroll
            for (int j = 0; j < KC / 4; ++j) {
                float4 xv = xp[j];   // wave-uniform address -> scalar load, SGPR broadcast
                p0 = fmaf(xv.x, w1r[4 * j + 0], p0);
                q0 = fmaf(xv.x, w2r[4 * j + 0], q0);
                p1 = fmaf(xv.y, w1r[4 * j + 1], p1);
                q1 = fmaf(xv.y, w2r[4 * j + 1], q1);
                p2 = fmaf(xv.z, w1r[4 * j + 2], p2);
                q2 = fmaf(xv.z, w2r[4 * j + 2], q2);
                p3 = fmaf(xv.w, w1r[4 * j + 3], p3);
                q3 = fmaf(xv.w, w2r[4 * j + 3], q3);
            }
            // 4 interleaved partials, pairwise combine, fp64 master accumulate:
            // keeps |error| ~1e-7 so topk ranks match an fp32 numpy reference.
            acc1[t] += (double)((p0 + p1) + (p2 + p3));
            acc2[t] += (double)((q0 + q1) + (q2 + q3));
        }
    }

    const float b1v = b1[lane];
    const float b2v = b2[lane];

    for (int t = 0; t < TPW; ++t) {
        const size_t tok = (size_t)(tok0 + t);
        const float z1 = (float)acc1[t] + b1v;
        const float z2 = (float)acc2[t] + b2v;
        // softplus in fp64: its error multiplies noise ~N(0,1) and feeds topk ordering
        const float sc = (float)log1p(exp((double)z2));
        const float nz = noise[tok * NE + lane];
        const float mixed = z1 + nz * sc;

        // full softmax across the wave (lane = expert)
        float vmax = mixed;
        for (int off = 32; off; off >>= 1) vmax = fmaxf(vmax, __shfl_xor(vmax, off));
        const float e = expf(mixed - vmax);
        float denom = e;
        for (int off = 32; off; off >>= 1) denom += __shfl_xor(denom, off);
        const float fullv = e / denom;

        // top-8 by iterative butterfly argmax, tie-break: lowest index (matches lax.top_k)
        float cur = mixed;
        int   sel = 0;
        float myidxf = 0.0f;
        #pragma unroll
        for (int r = 0; r < NK; ++r) {
            float bv = cur; int bi = lane;
            for (int off = 32; off; off >>= 1) {
                float ov = __shfl_xor(bv, off);
                int   oi = __shfl_xor(bi, off);
                if (ov > bv || (ov == bv && oi < bi)) { bv = ov; bi = oi; }
            }
            if (lane == r)  myidxf = (float)bi;   // r-th largest's index
            if (lane == bi) { sel = 1; cur = -INFINITY; }
        }

        // masked (sparse) softmax: top-1 max == vmax, reuse e
        const float es = sel ? e : 0.0f;
        float dsum = es;
        for (int off = 32; off; off >>= 1) dsum += __shfl_xor(dsum, off);
        const float sparsev = sel ? (e / dsum) : 0.0f;

        out_full[tok * NE + lane]   = fullv;
        out_sparse[tok * NE + lane] = sparsev;
        if (lane < NK) out_idx[tok * NK + lane] = myidxf;
    }
}

extern "C" void kernel_launch(void* const* d_in, const int* in_sizes, int n_in,
                              void* d_out, int out_size, void* d_ws, size_t ws_size,
                              hipStream_t stream) {
    const float* x     = (const float*)d_in[0];
    const float* noise = (const float*)d_in[1];
    const float* W1    = (const float*)d_in[2];
    const float* b1    = (const float*)d_in[3];
    const float* W2    = (const float*)d_in[4];
    const float* b2    = (const float*)d_in[5];

    float* out_sparse = (float*)d_out;                         // [16384*64]
    float* out_idx    = out_sparse + (size_t)NTOK * NE;        // [16384*8] as float
    float* out_full   = out_idx + (size_t)NTOK * NK;           // [16384*64]

    dim3 grid(NTOK / (4 * TPW));   // 512 workgroups x 256 threads (4 waves x 8 tokens)
    router_kernel<<<grid, 256, 0, stream>>>(x, noise, W1, b1, W2, b2,
                                            out_sparse, out_idx, out_full);
}

// Round 2
// 389.610 us; speedup vs baseline: 1.5770x; 1.5770x over previous
//
#include <hip/hip_runtime.h>
#include <math.h>

// NoisyTopkRouter: x[16384,2048] -> two skinny GEMMs vs W1/W2[2048,64],
// mixed = (xW1+b1) + noise*softplus(xW2+b2); outputs:
//   out0 sparse softmax [16384,64], out1 topk idx as float [16384,8], out2 full softmax [16384,64]
//
// R2 design: lane = expert (wave64 == 64 experts). Wave owns TPW=4 tokens.
// NO LDS, NO barriers (R1 post-mortem: LDS copy was folded into per-token
// ds_read re-reads -> LDS-issue-bound at VALUBusy=21%). W chunk now loaded
// straight from global (coalesced, L1/L2-resident: W is only 1 MB) into
// register arrays the compiler actually keeps. 1024 blocks -> 16 waves/CU.
// fp32 FMA partials + fp64 chunk accumulation preserve topk-grade accuracy.

constexpr int ND    = 2048;   // n_embed
constexpr int NE    = 64;     // experts
constexpr int NK    = 8;      // top_k
constexpr int TPW   = 4;      // tokens per wave
constexpr int KC    = 32;     // K chunk
constexpr int NTOK  = 16384;  // B*S

__global__ __launch_bounds__(256, 4)
void router_kernel(const float* __restrict__ x,
                   const float* __restrict__ noise,
                   const float* __restrict__ W1,
                   const float* __restrict__ b1,
                   const float* __restrict__ W2,
                   const float* __restrict__ b2,
                   float* __restrict__ out_sparse,
                   float* __restrict__ out_idx,
                   float* __restrict__ out_full)
{
    const int lane = threadIdx.x & 63;
    const int wv   = __builtin_amdgcn_readfirstlane((int)(threadIdx.x >> 6));
    const long tok0 = ((long)blockIdx.x * 4 + wv) * TPW;

    double acc1[TPW], acc2[TPW];
    #pragma unroll
    for (int t = 0; t < TPW; ++t) { acc1[t] = 0.0; acc2[t] = 0.0; }

    for (int kc = 0; kc < ND; kc += KC) {
        // W chunk -> registers, direct from global. Lane-consecutive dwords:
        // one coalesced 256B request per j; W (1 MB) stays in L1/L2.
        float w1r[KC], w2r[KC];
        #pragma unroll
        for (int j = 0; j < KC; ++j) {
            w1r[j] = W1[(size_t)(kc + j) * NE + lane];
            w2r[j] = W2[(size_t)(kc + j) * NE + lane];
        }

        #pragma unroll
        for (int t = 0; t < TPW; ++t) {
            const float4* xp = (const float4*)(x + (size_t)(tok0 + t) * ND + kc);
            float p0 = 0.f, p1 = 0.f, p2 = 0.f, p3 = 0.f;
            float q0 = 0.f, q1 = 0.f, q2 = 0.f, q3 = 0.f;
            #pragma unroll
            for (int j = 0; j < KC / 4; ++j) {
                float4 xv = xp[j];   // wave-uniform address: scalar-cache path
                p0 = fmaf(xv.x, w1r[4 * j + 0], p0);
                q0 = fmaf(xv.x, w2r[4 * j + 0], q0);
                p1 = fmaf(xv.y, w1r[4 * j + 1], p1);
                q1 = fmaf(xv.y, w2r[4 * j + 1], q1);
                p2 = fmaf(xv.z, w1r[4 * j + 2], p2);
                q2 = fmaf(xv.z, w2r[4 * j + 2], q2);
                p3 = fmaf(xv.w, w1r[4 * j + 3], p3);
                q3 = fmaf(xv.w, w2r[4 * j + 3], q3);
            }
            // 4 interleaved partials (ILP), pairwise combine, fp64 master
            // accumulate: keeps |error| ~1e-7 so topk ranks match reference.
            acc1[t] += (double)((p0 + p1) + (p2 + p3));
            acc2[t] += (double)((q0 + q1) + (q2 + q3));
        }
    }

    const float b1v = b1[lane];
    const float b2v = b2[lane];

    for (int t = 0; t < TPW; ++t) {
        const size_t tok = (size_t)(tok0 + t);
        const float z1 = (float)acc1[t] + b1v;
        const float z2 = (float)acc2[t] + b2v;
        // softplus in fp64: its error multiplies noise ~N(0,1) and feeds topk
        const float sc = (float)log1p(exp((double)z2));
        const float nz = noise[tok * NE + lane];
        const float mixed = z1 + nz * sc;

        // full softmax across the wave (lane = expert)
        float vmax = mixed;
        for (int off = 32; off; off >>= 1) vmax = fmaxf(vmax, __shfl_xor(vmax, off));
        const float e = expf(mixed - vmax);
        float denom = e;
        for (int off = 32; off; off >>= 1) denom += __shfl_xor(denom, off);
        const float fullv = e / denom;

        // top-8 by iterative butterfly argmax, tie-break: lowest index
        float cur = mixed;
        int   sel = 0;
        float myidxf = 0.0f;
        #pragma unroll
        for (int r = 0; r < NK; ++r) {
            float bv = cur; int bi = lane;
            for (int off = 32; off; off >>= 1) {
                float ov = __shfl_xor(bv, off);
                int   oi = __shfl_xor(bi, off);
                if (ov > bv || (ov == bv && oi < bi)) { bv = ov; bi = oi; }
            }
            if (lane == r)  myidxf = (float)bi;   // r-th largest's index
            if (lane == bi) { sel = 1; cur = -INFINITY; }
        }

        // masked (sparse) softmax: top-1 max == vmax, reuse e
        const float es = sel ? e : 0.0f;
        float dsum = es;
        for (int off = 32; off; off >>= 1) dsum += __shfl_xor(dsum, off);
        const float sparsev = sel ? (e / dsum) : 0.0f;

        out_full[tok * NE + lane]   = fullv;
        out_sparse[tok * NE + lane] = sparsev;
        if (lane < NK) out_idx[tok * NK + lane] = myidxf;
    }
}

extern "C" void kernel_launch(void* const* d_in, const int* in_sizes, int n_in,
                              void* d_out, int out_size, void* d_ws, size_t ws_size,
                              hipStream_t stream) {
    const float* x     = (const float*)d_in[0];
    const float* noise = (const float*)d_in[1];
    const float* W1    = (const float*)d_in[2];
    const float* b1    = (const float*)d_in[3];
    const float* W2    = (const float*)d_in[4];
    const float* b2    = (const float*)d_in[5];

    float* out_sparse = (float*)d_out;                         // [16384*64]
    float* out_idx    = out_sparse + (size_t)NTOK * NE;        // [16384*8] as float
    float* out_full   = out_idx + (size_t)NTOK * NK;           // [16384*64]

    dim3 grid(NTOK / (4 * TPW));   // 1024 workgroups x 256 threads (4 waves x 4 tokens)
    router_kernel<<<grid, 256, 0, stream>>>(x, noise, W1, b1, W2, b2,
                                            out_sparse, out_idx, out_full);
}

// Round 3
// 374.894 us; speedup vs baseline: 1.6389x; 1.0393x over previous
//
#include <hip/hip_runtime.h>
#include <math.h>

// NoisyTopkRouter: x[16384,2048] -> two skinny GEMMs vs W1/W2[2048,64],
// mixed = (xW1+b1) + noise*softplus(xW2+b2); outputs:
//   out0 sparse softmax [16384,64], out1 topk idx as float [16384,8], out2 full softmax [16384,64]
//
// R3 design: lane = expert (wave64 == 64 experts). Wave owns TPW=4 tokens.
// Loop order j-OUTER / t-INNER: every W element and x float4 has exactly ONE
// consumption point, so the register allocator cannot profitably rematerialize
// loads (R2 post-mortem: t-outer gave each W value 4 use points -> compiler
// re-issued 256 W loads/chunk instead of 64 -> VMEM-issue-bound, VALUBusy 42%).
// fp32 FMA partials (4 interleaved chains of 8) + fp64 chunk fold: identical
// numerics to R2 (passed, absmax 2e-3 << threshold) for topk rank fidelity.

constexpr int ND    = 2048;   // n_embed
constexpr int NE    = 64;     // experts
constexpr int NK    = 8;      // top_k
constexpr int TPW   = 4;      // tokens per wave
constexpr int KC    = 32;     // K chunk (fp64 fold granularity)
constexpr int NTOK  = 16384;  // B*S

__global__ __launch_bounds__(256, 4)
void router_kernel(const float* __restrict__ x,
                   const float* __restrict__ noise,
                   const float* __restrict__ W1,
                   const float* __restrict__ b1,
                   const float* __restrict__ W2,
                   const float* __restrict__ b2,
                   float* __restrict__ out_sparse,
                   float* __restrict__ out_idx,
                   float* __restrict__ out_full)
{
    const int lane = threadIdx.x & 63;
    const int wv   = __builtin_amdgcn_readfirstlane((int)(threadIdx.x >> 6));
    const long tok0 = ((long)blockIdx.x * 4 + wv) * TPW;

    double acc1[TPW], acc2[TPW];
    #pragma unroll
    for (int t = 0; t < TPW; ++t) { acc1[t] = 0.0; acc2[t] = 0.0; }

    for (int kc = 0; kc < ND; kc += KC) {
        // 4 interleaved fp32 partial chains (8 terms each) per token per GEMM
        float p0[TPW], p1[TPW], p2[TPW], p3[TPW];
        float q0[TPW], q1[TPW], q2[TPW], q3[TPW];
        #pragma unroll
        for (int t = 0; t < TPW; ++t) {
            p0[t] = p1[t] = p2[t] = p3[t] = 0.f;
            q0[t] = q1[t] = q2[t] = q3[t] = 0.f;
        }

        #pragma unroll
        for (int j = 0; j < KC; j += 4) {
            // W elements: loaded once, consumed at this single j-step (4 FMAs
            // each). Lane-consecutive dwords -> one coalesced 256B request;
            // W (1 MB) is L1/L2-resident.
            const size_t wb = (size_t)(kc + j) * NE + lane;
            const float w10 = W1[wb];          const float w20 = W2[wb];
            const float w11 = W1[wb + NE];     const float w21 = W2[wb + NE];
            const float w12 = W1[wb + 2 * NE]; const float w22 = W2[wb + 2 * NE];
            const float w13 = W1[wb + 3 * NE]; const float w23 = W2[wb + 3 * NE];

            #pragma unroll
            for (int t = 0; t < TPW; ++t) {
                // wave-uniform x float4: single consumption point (8 FMAs)
                const float4 xv = *(const float4*)(x + (size_t)(tok0 + t) * ND + kc + j);
                p0[t] = fmaf(xv.x, w10, p0[t]);  q0[t] = fmaf(xv.x, w20, q0[t]);
                p1[t] = fmaf(xv.y, w11, p1[t]);  q1[t] = fmaf(xv.y, w21, q1[t]);
                p2[t] = fmaf(xv.z, w12, p2[t]);  q2[t] = fmaf(xv.z, w22, q2[t]);
                p3[t] = fmaf(xv.w, w13, p3[t]);  q3[t] = fmaf(xv.w, w23, q3[t]);
            }
        }

        // pairwise combine, fp64 master accumulate (1 cvt + 1 add per GEMM
        // per token per chunk ~ 12.5% of FMA cycles): topk-grade accuracy.
        #pragma unroll
        for (int t = 0; t < TPW; ++t) {
            acc1[t] += (double)((p0[t] + p1[t]) + (p2[t] + p3[t]));
            acc2[t] += (double)((q0[t] + q1[t]) + (q2[t] + q3[t]));
        }
    }

    const float b1v = b1[lane];
    const float b2v = b2[lane];

    for (int t = 0; t < TPW; ++t) {
        const size_t tok = (size_t)(tok0 + t);
        const float z1 = (float)acc1[t] + b1v;
        const float z2 = (float)acc2[t] + b2v;
        // softplus in fp64: its error multiplies noise ~N(0,1) and feeds topk
        const float sc = (float)log1p(exp((double)z2));
        const float nz = noise[tok * NE + lane];
        const float mixed = z1 + nz * sc;

        // full softmax across the wave (lane = expert)
        float vmax = mixed;
        for (int off = 32; off; off >>= 1) vmax = fmaxf(vmax, __shfl_xor(vmax, off));
        const float e = expf(mixed - vmax);
        float denom = e;
        for (int off = 32; off; off >>= 1) denom += __shfl_xor(denom, off);
        const float fullv = e / denom;

        // top-8 by iterative butterfly argmax, tie-break: lowest index
        float cur = mixed;
        int   sel = 0;
        float myidxf = 0.0f;
        #pragma unroll
        for (int r = 0; r < NK; ++r) {
            float bv = cur; int bi = lane;
            for (int off = 32; off; off >>= 1) {
                float ov = __shfl_xor(bv, off);
                int   oi = __shfl_xor(bi, off);
                if (ov > bv || (ov == bv && oi < bi)) { bv = ov; bi = oi; }
            }
            if (lane == r)  myidxf = (float)bi;   // r-th largest's index
            if (lane == bi) { sel = 1; cur = -INFINITY; }
        }

        // masked (sparse) softmax: top-1 max == vmax, reuse e
        const float es = sel ? e : 0.0f;
        float dsum = es;
        for (int off = 32; off; off >>= 1) dsum += __shfl_xor(dsum, off);
        const float sparsev = sel ? (e / dsum) : 0.0f;

        out_full[tok * NE + lane]   = fullv;
        out_sparse[tok * NE + lane] = sparsev;
        if (lane < NK) out_idx[tok * NK + lane] = myidxf;
    }
}

extern "C" void kernel_launch(void* const* d_in, const int* in_sizes, int n_in,
                              void* d_out, int out_size, void* d_ws, size_t ws_size,
                              hipStream_t stream) {
    const float* x     = (const float*)d_in[0];
    const float* noise = (const float*)d_in[1];
    const float* W1    = (const float*)d_in[2];
    const float* b1    = (const float*)d_in[3];
    const float* W2    = (const float*)d_in[4];
    const float* b2    = (const float*)d_in[5];

    float* out_sparse = (float*)d_out;                         // [16384*64]
    float* out_idx    = out_sparse + (size_t)NTOK * NE;        // [16384*8] as float
    float* out_full   = out_idx + (size_t)NTOK * NK;           // [16384*64]

    dim3 grid(NTOK / (4 * TPW));   // 1024 workgroups x 256 threads (4 waves x 4 tokens)
    router_kernel<<<grid, 256, 0, stream>>>(x, noise, W1, b1, W2, b2,
                                            out_sparse, out_idx, out_full);
}

// Round 4
// 273.703 us; speedup vs baseline: 2.2448x; 1.3697x over previous
//
#include <hip/hip_runtime.h>
#include <math.h>

// NoisyTopkRouter via f16-split MFMA emulation of fp32 GEMM.
//   mixed = (x@W1+b1) + noise*softplus(x@W2+b2); outputs: sparse softmax,
//   topk idx (as float), full softmax.
//
// R4 design (post-mortem R3: scalar-FMA path is VALU-structural-bound at
// ~129us of VALU time vs 55us FMA floor; MFMA is the only lever past it):
//  - Split x and W into f16 planes: v = hi + lo*2^-11 (lo stored pre-scaled
//    by 2^11 so it stays normal). 3 MFMA passes: hi*hi -> acc0,
//    hi*lo + lo*hi -> acc1 (shared 2^11 scale). Products exact in fp32 acc;
//    dropped ll term ~2^-22 rel. fp64 fold every K=256 caps chain error.
//    Estimated |err| ~1.3e-7 vs np ref — same order as R3's passing kernel.
//  - Wave = 16 tokens (MFMA M), 8 N-tiles (64+64 experts). 4 waves/WG,
//    grid 256. W planes pre-split+transposed [n][k] into d_ws by prep kernel.
//  - Per K=32 chunk: W staged by global_load_lds (16B, XOR slot swizzle for
//    bank spread); x loaded fp32, split in regs, ds_written to per-wave LDS
//    (private -> no barrier). ONE __syncthreads per chunk; next chunk's
//    global loads issued after it so they overlap this chunk's compute.

typedef _Float16 f16x8 __attribute__((ext_vector_type(8)));
typedef _Float16 f16x4 __attribute__((ext_vector_type(4)));
typedef float f32x4 __attribute__((ext_vector_type(4)));

constexpr int ND = 2048, NE = 64, NK = 8, NTOK = 16384;
constexpr int KC   = 32;            // k per chunk = one MFMA K
constexpr int NCH  = ND / KC;       // 64 chunks
constexpr int WBUF = 2 * 128 * KC;  // f16 per W buffer (2 planes x 128 rows x 32)
constexpr int XROW = KC + 8;        // padded x row (f16) to spread banks
constexpr int XPW  = 2 * 16 * XROW; // per-wave x region (2 planes x 16 tok)
constexpr int XOFF = 2 * WBUF;      // start of x region in LDS

// ---- prep: split W1|W2 columns -> f16 hi / lo*2^11 planes, layout [plane][n][k]
__global__ void prep_w(const float* __restrict__ W1, const float* __restrict__ W2,
                       _Float16* __restrict__ wt) {
    const int n   = blockIdx.x;          // 0..127 (0..63 = W1 cols, 64..127 = W2)
    const float* W = (n < 64) ? W1 : W2;
    const int col = n & 63;
    const int k0  = threadIdx.x * 8;     // 256 thr x 8 = 2048
    _Float16 h[8], l[8];
    #pragma unroll
    for (int j = 0; j < 8; ++j) {
        const float v = W[(size_t)(k0 + j) * 64 + col];
        const _Float16 hh = (_Float16)v;
        const float r = v - (float)hh;       // exact residual
        h[j] = hh;
        l[j] = (_Float16)(r * 2048.0f);      // pre-scaled lo plane
    }
    *(f16x8*)&wt[(size_t)n * 2048 + k0]         = *(f16x8*)h;
    *(f16x8*)&wt[(size_t)(128 + n) * 2048 + k0] = *(f16x8*)l;
}

__global__ __launch_bounds__(256, 1)
void router_mfma(const float* __restrict__ x, const float* __restrict__ noise,
                 const _Float16* __restrict__ wt,
                 const float* __restrict__ b1, const float* __restrict__ b2,
                 float* __restrict__ out_sparse, float* __restrict__ out_idx,
                 float* __restrict__ out_full)
{
    __shared__ _Float16 lds[XOFF + 4 * XPW];   // 21504 f16 = 43 KB
    const int tid  = threadIdx.x;
    const int lane = tid & 63;
    const int wu   = __builtin_amdgcn_readfirstlane(tid >> 6);
    const int col  = lane & 15;      // MFMA col / token-row for A
    const int quad = lane >> 4;
    const long tok0 = (long)blockIdx.x * 64 + wu * 16;

    // W staging geometry: wave stages 64 of 256 (plane,row) rows per chunk
    const int wpl  = wu >> 1;              // plane this wave stages
    const int wn0  = (wu & 1) * 64;        // first row
    const int srow = lane >> 2;            // row within 16-row group
    const int sslot= lane & 3;             // 16B slot within 64B row

    f32x4 acc0[8], acc1[8];
    double zm[32];
    #pragma unroll
    for (int t = 0; t < 8; ++t)
        #pragma unroll
        for (int r = 0; r < 4; ++r) { acc0[t][r] = 0.f; acc1[t][r] = 0.f; zm[t*4+r] = 0.0; }

    float4 xv[2];

    auto stage_w = [&](int c, int buf) {
        const int kc = c * KC;
        #pragma unroll
        for (int g = 0; g < 4; ++g) {
            const int n = wn0 + g * 16 + srow;
            const int gslot = sslot ^ (n & 3) ^ ((n >> 2) & 3);   // XOR bank swizzle
            const _Float16* gsrc = wt + (size_t)(wpl * 128 + n) * 2048 + kc + gslot * 8;
            _Float16* ldst = &lds[(size_t)buf * WBUF + (size_t)wpl * 4096 + (wn0 + g * 16) * KC];
            __builtin_amdgcn_global_load_lds(
                (const __attribute__((address_space(1))) void*)gsrc,
                (__attribute__((address_space(3))) void*)ldst, 16, 0, 0);
        }
    };

    auto load_x = [&](int c) {
        const int kc = c * KC;
        #pragma unroll
        for (int u = 0; u < 2; ++u) {
            const int f = u * 64 + lane;
            const int t = f >> 3, s = f & 7;      // token row, float4 slot
            xv[u] = *(const float4*)(x + (tok0 + t) * ND + kc + s * 4);
        }
    };

    auto store_x = [&]() {
        _Float16* xb = &lds[XOFF + wu * XPW];
        #pragma unroll
        for (int u = 0; u < 2; ++u) {
            const int f = u * 64 + lane;
            const int t = f >> 3, s = f & 7;
            const float4 v = xv[u];
            const _Float16 h0 = (_Float16)v.x, h1 = (_Float16)v.y,
                           h2 = (_Float16)v.z, h3 = (_Float16)v.w;
            const f16x4 hv = {h0, h1, h2, h3};
            const f16x4 lv = { (_Float16)((v.x - (float)h0) * 2048.0f),
                               (_Float16)((v.y - (float)h1) * 2048.0f),
                               (_Float16)((v.z - (float)h2) * 2048.0f),
                               (_Float16)((v.w - (float)h3) * 2048.0f) };
            *(f16x4*)&xb[t * XROW + s * 4]             = hv;
            *(f16x4*)&xb[16 * XROW + t * XROW + s * 4] = lv;
        }
    };

    auto compute = [&](int buf) {
        const _Float16* xb = &lds[XOFF + wu * XPW];
        const _Float16* wb = &lds[buf * WBUF];
        // A frags: A[m=lane&15][k=quad*8+j]
        const f16x8 ah = *(const f16x8*)&xb[col * XROW + quad * 8];
        const f16x8 al = *(const f16x8*)&xb[16 * XROW + col * XROW + quad * 8];
        // B frags: B[k=quad*8+j][n=lane&15], row = tile*16+col, swizzled slot
        const int sx = quad ^ (col & 3) ^ ((col >> 2) & 3);
        f16x8 bh[8], bl[8];
        #pragma unroll
        for (int t = 0; t < 8; ++t) {
            const int row = t * 16 + col;
            bh[t] = *(const f16x8*)&wb[row * KC + sx * 8];
            bl[t] = *(const f16x8*)&wb[4096 + row * KC + sx * 8];
        }
        // 3 passes, dependent acc1 MFMAs separated by 7 independents
        #pragma unroll
        for (int t = 0; t < 8; ++t)
            acc0[t] = __builtin_amdgcn_mfma_f32_16x16x32_f16(ah, bh[t], acc0[t], 0, 0, 0);
        #pragma unroll
        for (int t = 0; t < 8; ++t)
            acc1[t] = __builtin_amdgcn_mfma_f32_16x16x32_f16(ah, bl[t], acc1[t], 0, 0, 0);
        #pragma unroll
        for (int t = 0; t < 8; ++t)
            acc1[t] = __builtin_amdgcn_mfma_f32_16x16x32_f16(al, bh[t], acc1[t], 0, 0, 0);
    };

    stage_w(0, 0);
    load_x(0);
    for (int c = 0; c < NCH; ++c) {
        const int buf = c & 1;
        __syncthreads();                    // waits chunk-c W deposits + x regs
        if (c + 1 < NCH) stage_w(c + 1, buf ^ 1);   // flies across compute(c)
        store_x();
        if (c + 1 < NCH) load_x(c + 1);             // flies across compute(c)
        compute(buf);
        if ((c & 7) == 7) {                 // fold every K=256 into fp64
            #pragma unroll
            for (int t = 0; t < 8; ++t)
                #pragma unroll
                for (int r = 0; r < 4; ++r) {
                    zm[t*4+r] += (double)acc0[t][r]
                               + (double)(acc1[t][r] * 4.8828125e-4f);  // 2^-11
                    acc0[t][r] = 0.f; acc1[t][r] = 0.f;
                }
        }
    }

    // ---- epilogue: C/D layout D[m=quad*4+reg][n=lane&15]
    float b1v[4], b2v[4];
    #pragma unroll
    for (int t = 0; t < 4; ++t) { b1v[t] = b1[t*16 + col]; b2v[t] = b2[t*16 + col]; }

    #pragma unroll
    for (int r = 0; r < 4; ++r) {
        const long tk = tok0 + quad * 4 + r;
        float mixed[4], ee[4];
        #pragma unroll
        for (int t = 0; t < 4; ++t) {
            const float z1 = (float)zm[t*4+r]       + b1v[t];
            const float z2 = (float)zm[(t+4)*4+r]   + b2v[t];
            const float sp = (float)log1p(exp((double)z2));   // f64 softplus
            const float nz = noise[tk * NE + t*16 + col];
            mixed[t] = z1 + nz * sp;
        }
        // full softmax over 64 experts: 4 local + butterfly over 16 lanes (quad-local)
        float vmax = fmaxf(fmaxf(mixed[0], mixed[1]), fmaxf(mixed[2], mixed[3]));
        #pragma unroll
        for (int off = 8; off >= 1; off >>= 1) vmax = fmaxf(vmax, __shfl_xor(vmax, off));
        float denom = 0.f;
        #pragma unroll
        for (int t = 0; t < 4; ++t) { ee[t] = expf(mixed[t] - vmax); denom += ee[t]; }
        #pragma unroll
        for (int off = 8; off >= 1; off >>= 1) denom += __shfl_xor(denom, off);

        // top-8: iterative argmax, tie-break lowest index
        float cur[4] = {mixed[0], mixed[1], mixed[2], mixed[3]};
        int selm = 0;
        float idxout = 0.f;
        #pragma unroll
        for (int rr = 0; rr < NK; ++rr) {
            float bv = cur[0]; int bn = col;
            #pragma unroll
            for (int t = 1; t < 4; ++t)
                if (cur[t] > bv) { bv = cur[t]; bn = t*16 + col; }   // strict >: lower tile wins ties
            #pragma unroll
            for (int off = 8; off >= 1; off >>= 1) {
                const float ov = __shfl_xor(bv, off);
                const int   on = __shfl_xor(bn, off);
                if (ov > bv || (ov == bv && on < bn)) { bv = ov; bn = on; }
            }
            if (col == rr) idxout = (float)bn;
            #pragma unroll
            for (int t = 0; t < 4; ++t)
                if (bn == t*16 + col) { selm |= 1 << t; cur[t] = -INFINITY; }
        }
        float ssum = 0.f;
        #pragma unroll
        for (int t = 0; t < 4; ++t) if (selm & (1 << t)) ssum += ee[t];
        #pragma unroll
        for (int off = 8; off >= 1; off >>= 1) ssum += __shfl_xor(ssum, off);

        #pragma unroll
        for (int t = 0; t < 4; ++t) {
            const size_t o = (size_t)tk * NE + t*16 + col;
            out_full[o]   = ee[t] / denom;
            out_sparse[o] = (selm & (1 << t)) ? ee[t] / ssum : 0.f;
        }
        if (col < NK) out_idx[tk * NK + col] = idxout;
    }
}

extern "C" void kernel_launch(void* const* d_in, const int* in_sizes, int n_in,
                              void* d_out, int out_size, void* d_ws, size_t ws_size,
                              hipStream_t stream) {
    const float* x     = (const float*)d_in[0];
    const float* noise = (const float*)d_in[1];
    const float* W1    = (const float*)d_in[2];
    const float* b1    = (const float*)d_in[3];
    const float* W2    = (const float*)d_in[4];
    const float* b2    = (const float*)d_in[5];

    float* out_sparse = (float*)d_out;                      // [16384*64]
    float* out_idx    = out_sparse + (size_t)NTOK * NE;     // [16384*8]
    float* out_full   = out_idx + (size_t)NTOK * NK;        // [16384*64]

    _Float16* wt = (_Float16*)d_ws;   // 2 planes x 128 x 2048 f16 = 1 MB

    prep_w<<<128, 256, 0, stream>>>(W1, W2, wt);
    router_mfma<<<256, 256, 0, stream>>>(x, noise, wt, b1, b2,
                                         out_sparse, out_idx, out_full);
}

// Round 6
// 255.813 us; speedup vs baseline: 2.4018x; 1.0699x over previous
//
#include <hip/hip_runtime.h>
#include <math.h>

// NoisyTopkRouter via f16-split MFMA (hi + lo*2^-11 planes, 3 passes).
// R6 = R5 with the ws-offset precedence bug fixed ((size_t)1<<20 parenthesized).
// R5 design rationale (vs R4's latency collapse at grid=256, 11.8% occupancy):
//  - 32-token blocks x 2-way K-split -> grid 1024 = 4 blocks/CU, 16 waves/CU.
//  - W pre-swizzled into MFMA fragment order -> B frags load straight from
//    global (L2, 1 MB) as coalesced dwordx4: no LDS for B, no bank conflicts.
//  - LDS only for the x fp32->f16x2 transpose (10 KB, double-buffered).
//  - K-split partials: plain fp32 slices in d_ws (16 MB, no atomics/memset);
//    epilogue kernel combines in fp64 + proven 64-lane butterfly
//    softmax/top8/masked-softmax.
// d_ws budget: 1 MB (wt3) + 16 MB (zpart) = 17 MB.

typedef _Float16 f16x8 __attribute__((ext_vector_type(8)));
typedef _Float16 f16x4 __attribute__((ext_vector_type(4)));
typedef float f32x4 __attribute__((ext_vector_type(4)));

constexpr int ND = 2048, NE = 64, NK = 8, NTOK = 16384;
constexpr int KC   = 32;          // k per chunk (one MFMA K)
constexpr int NCHT = ND / KC;     // 64 chunks total
constexpr int KS   = 2;           // K-split ways
constexpr int CPS  = NCHT / KS;   // 32 chunks per segment
constexpr int MTOK = 32;          // tokens per block
constexpr int XROW = 40;          // padded f16 row (80 B, 16B-aligned rows)
constexpr int XPLANE = MTOK * XROW;   // 1280 f16
constexpr int XBUF   = 2 * XPLANE;    // hi+lo planes per buffer

// ---- prep: W1|W2 -> f16 hi / lo*2^11 planes in MFMA B-fragment order.
// Layout: frag(cg, p, t) at ((cg*2+p)*8 + t)*512 + lane*8, cg=0..63 chunk,
// p=plane, t=N-tile (0-3: W1 cols, 4-7: W2 cols), lane=(quad<<4)|col.
__global__ void prep_w(const float* __restrict__ W1, const float* __restrict__ W2,
                       _Float16* __restrict__ wt3) {
    const int g    = blockIdx.x * 256 + threadIdx.x;   // 0..32767
    const int cg   = g >> 9;
    const int rem  = g & 511;
    const int t    = rem >> 6;
    const int lane = rem & 63;
    const int col  = lane & 15, q = lane >> 4;
    const int n    = t * 16 + col;
    const float* W = (t < 4) ? W1 : W2;
    const int cn   = n & 63;
    _Float16 h[8], l[8];
    #pragma unroll
    for (int j = 0; j < 8; ++j) {
        const float v = W[(size_t)(cg * 32 + q * 8 + j) * 64 + cn];
        const _Float16 hh = (_Float16)v;
        h[j] = hh;
        l[j] = (_Float16)((v - (float)hh) * 2048.0f);   // pre-scaled lo plane
    }
    *(f16x8*)&wt3[((size_t)(cg * 2 + 0) * 8 + t) * 512 + lane * 8] = *(f16x8*)h;
    *(f16x8*)&wt3[((size_t)(cg * 2 + 1) * 8 + t) * 512 + lane * 8] = *(f16x8*)l;
}

// ---- main: per block 32 tokens x all 128 cols x K=1024 (one kseg).
__global__ __launch_bounds__(256, 4)
void router_main(const float* __restrict__ x, const _Float16* __restrict__ wt3,
                 float* __restrict__ zpart) {
    __shared__ _Float16 xlds[2 * XBUF];   // 10 KB
    const int tid  = threadIdx.x;
    const int lane = tid & 63;
    const int wu   = __builtin_amdgcn_readfirstlane(tid >> 6);
    const int col  = lane & 15, q = lane >> 4;
    const int mg   = blockIdx.x >> 1;          // 0..511 token group
    const int ks   = blockIdx.x & 1;           // k segment
    const long tok0 = (long)mg * MTOK;
    const int c0   = ks * CPS;
    const int ta   = 2 * wu, tb = 2 * wu + 1;  // this wave's N-tiles

    // x loader mapping: 8 threads cover one token's 32-float chunk (128 B)
    const int ltok = tid >> 3;       // 0..31
    const int lsub = tid & 7;        // float4 slot
    const float* xbase = x + (tok0 + ltok) * (size_t)ND + (size_t)c0 * KC + lsub * 4;

    f32x4 a0[2][2], a1[2][2];
    #pragma unroll
    for (int m = 0; m < 2; ++m)
        #pragma unroll
        for (int i = 0; i < 2; ++i)
            #pragma unroll
            for (int r = 0; r < 4; ++r) { a0[m][i][r] = 0.f; a1[m][i][r] = 0.f; }

    float4 xv = *(const float4*)xbase;   // chunk-0 preload

    for (int c = 0; c < CPS; ++c) {
        _Float16* xb = &xlds[(c & 1) * XBUF];

        // split this chunk's x and deposit (wave-private rows, block-shared read)
        {
            const _Float16 h0 = (_Float16)xv.x, h1 = (_Float16)xv.y,
                           h2 = (_Float16)xv.z, h3 = (_Float16)xv.w;
            const f16x4 hv = {h0, h1, h2, h3};
            const f16x4 lv = { (_Float16)((xv.x - (float)h0) * 2048.0f),
                               (_Float16)((xv.y - (float)h1) * 2048.0f),
                               (_Float16)((xv.z - (float)h2) * 2048.0f),
                               (_Float16)((xv.w - (float)h3) * 2048.0f) };
            *(f16x4*)&xb[ltok * XROW + lsub * 4]          = hv;
            *(f16x4*)&xb[XPLANE + ltok * XROW + lsub * 4] = lv;
        }
        __syncthreads();

        // B fragments straight from global (L2-resident, coalesced dwordx4)
        const size_t fb = (size_t)(c0 + c) * 2 * 8 * 512 + (size_t)lane * 8;
        const f16x8 bha = *(const f16x8*)&wt3[fb + ta * 512];
        const f16x8 bhb = *(const f16x8*)&wt3[fb + tb * 512];
        const f16x8 bla = *(const f16x8*)&wt3[fb + 8 * 512 + ta * 512];
        const f16x8 blb = *(const f16x8*)&wt3[fb + 8 * 512 + tb * 512];

        // next chunk's x flies across this chunk's compute
        if (c + 1 < CPS) xv = *(const float4*)(xbase + (c + 1) * KC);

        #pragma unroll
        for (int mt = 0; mt < 2; ++mt) {
            const f16x8 ah = *(const f16x8*)&xb[(mt * 16 + col) * XROW + q * 8];
            const f16x8 al = *(const f16x8*)&xb[XPLANE + (mt * 16 + col) * XROW + q * 8];
            a0[mt][0] = __builtin_amdgcn_mfma_f32_16x16x32_f16(ah, bha, a0[mt][0], 0, 0, 0);
            a0[mt][1] = __builtin_amdgcn_mfma_f32_16x16x32_f16(ah, bhb, a0[mt][1], 0, 0, 0);
            a1[mt][0] = __builtin_amdgcn_mfma_f32_16x16x32_f16(ah, bla, a1[mt][0], 0, 0, 0);
            a1[mt][1] = __builtin_amdgcn_mfma_f32_16x16x32_f16(ah, blb, a1[mt][1], 0, 0, 0);
            a1[mt][0] = __builtin_amdgcn_mfma_f32_16x16x32_f16(al, bha, a1[mt][0], 0, 0, 0);
            a1[mt][1] = __builtin_amdgcn_mfma_f32_16x16x32_f16(al, bhb, a1[mt][1], 0, 0, 0);
        }
        __syncthreads();   // buf reuse protection
    }

    // fold hi+lo and store this kseg's fp32 partial slice
    // C/D layout: col = lane&15 (n within tile), row = q*4 + r (m within tile)
    float* zp = zpart + (size_t)ks * NTOK * 128;
    #pragma unroll
    for (int mt = 0; mt < 2; ++mt)
        #pragma unroll
        for (int i = 0; i < 2; ++i) {
            const int n = (2 * wu + i) * 16 + col;
            #pragma unroll
            for (int r = 0; r < 4; ++r) {
                const long token = tok0 + mt * 16 + q * 4 + r;
                zp[(size_t)token * 128 + n] = a0[mt][i][r] + a1[mt][i][r] * 4.8828125e-4f;
            }
        }
}

// ---- epilogue: combine ksegs (fp64), softplus, softmax/top8/masked softmax.
__global__ __launch_bounds__(256, 4)
void router_epi(const float* __restrict__ zpart, const float* __restrict__ noise,
                const float* __restrict__ b1, const float* __restrict__ b2,
                float* __restrict__ out_sparse, float* __restrict__ out_idx,
                float* __restrict__ out_full) {
    const int lane = threadIdx.x & 63;
    const int wu   = threadIdx.x >> 6;
    const float b1v = b1[lane];
    const float b2v = b2[lane];

    for (int tt = 0; tt < 4; ++tt) {
        const long tok = (long)blockIdx.x * 16 + wu * 4 + tt;
        const size_t r0 = (size_t)tok * 128;
        const size_t s1 = (size_t)NTOK * 128;
        const double z1d = (double)zpart[r0 + lane]      + (double)zpart[s1 + r0 + lane];
        const double z2d = (double)zpart[r0 + 64 + lane] + (double)zpart[s1 + r0 + 64 + lane];
        const float z1 = (float)z1d + b1v;
        const float z2 = (float)z2d + b2v;
        const float sc = (float)log1p(exp((double)z2));   // f64 softplus
        const float nz = noise[tok * NE + lane];
        const float mixed = z1 + nz * sc;

        // full softmax across the wave (lane = expert)
        float vmax = mixed;
        for (int off = 32; off; off >>= 1) vmax = fmaxf(vmax, __shfl_xor(vmax, off));
        const float e = expf(mixed - vmax);
        float denom = e;
        for (int off = 32; off; off >>= 1) denom += __shfl_xor(denom, off);
        const float fullv = e / denom;

        // top-8 iterative butterfly argmax, tie-break lowest index
        float cur = mixed;
        int   sel = 0;
        float myidxf = 0.0f;
        #pragma unroll
        for (int r = 0; r < NK; ++r) {
            float bv = cur; int bi = lane;
            for (int off = 32; off; off >>= 1) {
                const float ov = __shfl_xor(bv, off);
                const int   oi = __shfl_xor(bi, off);
                if (ov > bv || (ov == bv && oi < bi)) { bv = ov; bi = oi; }
            }
            if (lane == r)  myidxf = (float)bi;
            if (lane == bi) { sel = 1; cur = -INFINITY; }
        }

        const float es = sel ? e : 0.0f;
        float dsum = es;
        for (int off = 32; off; off >>= 1) dsum += __shfl_xor(dsum, off);
        const float sparsev = sel ? (e / dsum) : 0.0f;

        out_full[tok * NE + lane]   = fullv;
        out_sparse[tok * NE + lane] = sparsev;
        if (lane < NK) out_idx[tok * NK + lane] = myidxf;
    }
}

extern "C" void kernel_launch(void* const* d_in, const int* in_sizes, int n_in,
                              void* d_out, int out_size, void* d_ws, size_t ws_size,
                              hipStream_t stream) {
    const float* x     = (const float*)d_in[0];
    const float* noise = (const float*)d_in[1];
    const float* W1    = (const float*)d_in[2];
    const float* b1    = (const float*)d_in[3];
    const float* W2    = (const float*)d_in[4];
    const float* b2    = (const float*)d_in[5];

    float* out_sparse = (float*)d_out;                      // [16384*64]
    float* out_idx    = out_sparse + (size_t)NTOK * NE;     // [16384*8]
    float* out_full   = out_idx + (size_t)NTOK * NK;        // [16384*64]

    _Float16* wt3 = (_Float16*)d_ws;                              // 1 MB fragment-order W
    float* zpart  = (float*)((char*)d_ws + ((size_t)1 << 20));    // 16 MB partials [2][16384][128]

    prep_w<<<128, 256, 0, stream>>>(W1, W2, wt3);
    router_main<<<NTOK / MTOK * KS, 256, 0, stream>>>(x, wt3, zpart);   // 1024 blocks
    router_epi<<<NTOK / 16, 256, 0, stream>>>(zpart, noise, b1, b2,
                                              out_sparse, out_idx, out_full);
}